// Round 1
// baseline (59.879 us; speedup 1.0000x reference)
//
#include <hip/hip_runtime.h>

// LIF_BTN: y[t] = heaviside(tau*v[t-1] + x[t] - v_th), v[t] = m*(1-y[t])
// x: [T=32, B=32, N=32768] f32; y same shape/dtype.
// Memory-bound: 268 MB HBM traffic, roofline ~43 us @ 6.3 TB/s.

#define T_STEPS 32
#define TAU 0.5f
#define V_TH 1.0f

__global__ __launch_bounds__(256) void lif_btn_kernel(
    const float4* __restrict__ x, float4* __restrict__ y, int n4) {
    int idx = blockIdx.x * blockDim.x + threadIdx.x;
    if (idx >= n4) return;

    float4 v = make_float4(0.f, 0.f, 0.f, 0.f);

    #pragma unroll
    for (int t = 0; t < T_STEPS; ++t) {
        float4 xt = x[(size_t)t * n4 + idx];
        float4 m, out;
        m.x = TAU * v.x + xt.x;
        m.y = TAU * v.y + xt.y;
        m.z = TAU * v.z + xt.z;
        m.w = TAU * v.w + xt.w;
        out.x = (m.x >= V_TH) ? 1.f : 0.f;
        out.y = (m.y >= V_TH) ? 1.f : 0.f;
        out.z = (m.z >= V_TH) ? 1.f : 0.f;
        out.w = (m.w >= V_TH) ? 1.f : 0.f;
        // hard reset: v = m*(1-y) == (spike ? 0 : m)
        v.x = (m.x >= V_TH) ? 0.f : m.x;
        v.y = (m.y >= V_TH) ? 0.f : m.y;
        v.z = (m.z >= V_TH) ? 0.f : m.z;
        v.w = (m.w >= V_TH) ? 0.f : m.w;
        y[(size_t)t * n4 + idx] = out;
    }
}

extern "C" void kernel_launch(void* const* d_in, const int* in_sizes, int n_in,
                              void* d_out, int out_size, void* d_ws, size_t ws_size,
                              hipStream_t stream) {
    const float* x = (const float*)d_in[0];
    float* y = (float*)d_out;

    int total = in_sizes[0];        // T*B*N = 33554432
    int per_t = total / T_STEPS;    // B*N   = 1048576
    int n4 = per_t / 4;             // float4 chains per timestep = 262144

    const int block = 256;
    int grid = (n4 + block - 1) / block;  // 1024 blocks -> 16 waves/CU
    lif_btn_kernel<<<grid, block, 0, stream>>>(
        (const float4*)x, (float4*)y, n4);
}

// Round 2
// 51.874 us; speedup vs baseline: 1.1543x; 1.1543x over previous
//
#include <hip/hip_runtime.h>

// LIF_BTN: y[t] = heaviside(tau*v[t-1] + x[t] - v_th), v[t] = (spike ? 0 : m)
// x: [T=32, B=32, N=32768] f32; y same. Memory-bound, 268 MB total traffic.
// R1: explicit 8-deep double-buffered load pipeline (R0 was latency-bound at
// 28 VGPRs / ~2 loads in flight) + nontemporal stores to keep x resident in L3.

typedef float f32x4 __attribute__((ext_vector_type(4)));

#define T_STEPS 32
#define CHUNK 8
#define TAU 0.5f
#define V_TH 1.0f

__global__ __launch_bounds__(256) void lif_btn_kernel(
    const f32x4* __restrict__ x, f32x4* __restrict__ y, int n4) {
    int idx = blockIdx.x * blockDim.x + threadIdx.x;
    if (idx >= n4) return;

    const f32x4* xp = x + idx;
    f32x4* yp = y + idx;

    f32x4 v;
    v.x = 0.f; v.y = 0.f; v.z = 0.f; v.w = 0.f;

    f32x4 cur[CHUNK], nxt[CHUNK];

    // prologue: issue first chunk of loads
    #pragma unroll
    for (int i = 0; i < CHUNK; ++i)
        cur[i] = xp[(size_t)i * n4];

    #pragma unroll
    for (int c = 0; c < T_STEPS / CHUNK; ++c) {
        // prefetch next chunk (8 independent loads in flight over the compute)
        if (c + 1 < T_STEPS / CHUNK) {
            #pragma unroll
            for (int i = 0; i < CHUNK; ++i)
                nxt[i] = xp[(size_t)((c + 1) * CHUNK + i) * n4];
        }
        #pragma unroll
        for (int i = 0; i < CHUNK; ++i) {
            f32x4 m, out;
            m.x = TAU * v.x + cur[i].x;
            m.y = TAU * v.y + cur[i].y;
            m.z = TAU * v.z + cur[i].z;
            m.w = TAU * v.w + cur[i].w;
            out.x = (m.x >= V_TH) ? 1.f : 0.f;
            out.y = (m.y >= V_TH) ? 1.f : 0.f;
            out.z = (m.z >= V_TH) ? 1.f : 0.f;
            out.w = (m.w >= V_TH) ? 1.f : 0.f;
            v.x = (m.x >= V_TH) ? 0.f : m.x;
            v.y = (m.y >= V_TH) ? 0.f : m.y;
            v.z = (m.z >= V_TH) ? 0.f : m.z;
            v.w = (m.w >= V_TH) ? 0.f : m.w;
            // streaming write-once output: nt keeps L2/L3 for x
            __builtin_nontemporal_store(out, yp + (size_t)(c * CHUNK + i) * n4);
        }
        // rotate buffers (all indices compile-time after unroll -> stays in VGPRs)
        #pragma unroll
        for (int i = 0; i < CHUNK; ++i)
            cur[i] = nxt[i];
    }
}

extern "C" void kernel_launch(void* const* d_in, const int* in_sizes, int n_in,
                              void* d_out, int out_size, void* d_ws, size_t ws_size,
                              hipStream_t stream) {
    const float* x = (const float*)d_in[0];
    float* y = (float*)d_out;

    int total = in_sizes[0];        // T*B*N = 33554432
    int per_t = total / T_STEPS;    // B*N   = 1048576
    int n4 = per_t / 4;             // 262144 float4 chains

    const int block = 256;
    int grid = (n4 + block - 1) / block;  // 1024 blocks -> 16 waves/CU
    lif_btn_kernel<<<grid, block, 0, stream>>>(
        (const f32x4*)x, (f32x4*)y, n4);
}

// Round 3
// 43.870 us; speedup vs baseline: 1.3649x; 1.1824x over previous
//
#include <hip/hip_runtime.h>

// LIF_BTN: y[t] = heaviside(tau*v[t-1] + x[t] - v_th), v[t] = (spike ? 0 : m)
// x: [T=32, B=32, N=32768] f32; y same. Memory-bound: 134 MB write + ~67 MB
// HBM read (L3 serves the rest). Roofline ~35 us.
// R2: float2 per thread -> 8192 waves (32/CU, HW max TLP) vs R1's 4096;
// keep 8-deep prefetch window + nontemporal stores (saved RFO traffic in R1).

typedef float f32x2 __attribute__((ext_vector_type(2)));

#define T_STEPS 32
#define CHUNK 8
#define TAU 0.5f
#define V_TH 1.0f

__global__ __launch_bounds__(256) void lif_btn_kernel(
    const f32x2* __restrict__ x, f32x2* __restrict__ y, int n2) {
    int idx = blockIdx.x * blockDim.x + threadIdx.x;
    if (idx >= n2) return;

    const f32x2* xp = x + idx;
    f32x2* yp = y + idx;

    f32x2 v;
    v.x = 0.f; v.y = 0.f;

    f32x2 cur[CHUNK], nxt[CHUNK];

    #pragma unroll
    for (int i = 0; i < CHUNK; ++i)
        cur[i] = xp[(size_t)i * n2];

    #pragma unroll
    for (int c = 0; c < T_STEPS / CHUNK; ++c) {
        if (c + 1 < T_STEPS / CHUNK) {
            #pragma unroll
            for (int i = 0; i < CHUNK; ++i)
                nxt[i] = xp[(size_t)((c + 1) * CHUNK + i) * n2];
        }
        #pragma unroll
        for (int i = 0; i < CHUNK; ++i) {
            f32x2 m, out;
            m.x = TAU * v.x + cur[i].x;
            m.y = TAU * v.y + cur[i].y;
            out.x = (m.x >= V_TH) ? 1.f : 0.f;
            out.y = (m.y >= V_TH) ? 1.f : 0.f;
            v.x = (m.x >= V_TH) ? 0.f : m.x;
            v.y = (m.y >= V_TH) ? 0.f : m.y;
            __builtin_nontemporal_store(out, yp + (size_t)(c * CHUNK + i) * n2);
        }
        #pragma unroll
        for (int i = 0; i < CHUNK; ++i)
            cur[i] = nxt[i];
    }
}

extern "C" void kernel_launch(void* const* d_in, const int* in_sizes, int n_in,
                              void* d_out, int out_size, void* d_ws, size_t ws_size,
                              hipStream_t stream) {
    const float* x = (const float*)d_in[0];
    float* y = (float*)d_out;

    int total = in_sizes[0];        // T*B*N = 33554432
    int per_t = total / T_STEPS;    // B*N   = 1048576
    int n2 = per_t / 2;             // 524288 float2 chains

    const int block = 256;
    int grid = (n2 + block - 1) / block;  // 2048 blocks -> 32 waves/CU
    lif_btn_kernel<<<grid, block, 0, stream>>>(
        (const f32x2*)x, (f32x2*)y, n2);
}